// Round 11
// baseline (276.052 us; speedup 1.0000x reference)
//
#include <hip/hip_runtime.h>
#include <hip/hip_cooperative_groups.h>

namespace cg = cooperative_groups;

#define NDENSE 13
#define NSPARSE 26
#define ROW_F4 156     // fp32 v row = 156 float4
#define BATCH 4096
#define VROWS 26013
#define ROW_U32 160    // padded f8 row = 160 uint32 = 640 B = 5 x 128B slices
#define ROW_U4  40
#define ROW_U2  80     // uint2 stride per row
#define NSLICE 5
#define RECW   32      // packed row record: u[16], nrmc, w, pad -> 128 B
#define SQ_RPB 8       // rows per phase-2 unit
#define SQ_CHUNKS 512  // 4096/8
#define UNITS_PER_XCD 320  // 5*512/8

// ---------------- fp8 e4m3 (OCP) encode/decode --------------------------
#if defined(__has_builtin)
#if __has_builtin(__builtin_amdgcn_cvt_pk_fp8_f32) && __has_builtin(__builtin_amdgcn_cvt_pk_f32_fp8)
#define FP8_HW 1
#endif
#endif

typedef float f32x2 __attribute__((ext_vector_type(2)));

__device__ inline unsigned enc1(float f) {
    unsigned u = __float_as_uint(f);
    unsigned s = (u >> 24) & 0x80u;
    unsigned a = u & 0x7fffffffu;
    if (a >= 0x3c800000u) {
        unsigned r = a + 0x7ffffu + ((a >> 20) & 1u);
        return s | ((r - (120u << 23)) >> 20);
    }
    return s | (unsigned)__float2uint_rn(__uint_as_float(a) * 512.f);
}
__device__ inline float dec1(unsigned b) {
    unsigned em = b & 0x7fu;
    float mag = (em >= 8u) ? __uint_as_float((em << 20) + (120u << 23))
                           : (float)em * 0x1p-9f;
    return (b & 0x80u) ? -mag : mag;
}
__device__ inline unsigned enc4(float4 x) {
#ifdef FP8_HW
    int pk = 0;
    pk = __builtin_amdgcn_cvt_pk_fp8_f32(x.x, x.y, pk, false);
    pk = __builtin_amdgcn_cvt_pk_fp8_f32(x.z, x.w, pk, true);
    return (unsigned)pk;
#else
    return enc1(x.x) | (enc1(x.y) << 8) | (enc1(x.z) << 16) | (enc1(x.w) << 24);
#endif
}
__device__ inline float4 dec4(unsigned p) {
#ifdef FP8_HW
    f32x2 lo = __builtin_amdgcn_cvt_pk_f32_fp8((int)p, false);
    f32x2 hi = __builtin_amdgcn_cvt_pk_f32_fp8((int)p, true);
    return make_float4(lo.x, lo.y, hi.x, hi.y);
#else
    return make_float4(dec1(p & 0xffu), dec1((p >> 8) & 0xffu),
                       dec1((p >> 16) & 0xffu), dec1((p >> 24) & 0xffu));
#endif
}

// ---------------------------------------------------------------------------
// Cooperative fused kernel: prep -> grid.sync -> sq -> grid.sync -> out.
__global__ __launch_bounds__(256, 8) void ffm_coop(
    const float*  __restrict__ dense,
    const int*    __restrict__ sparse,
    const float*  __restrict__ w0,
    const float*  __restrict__ w,
    const float4* __restrict__ v4,
    unsigned*     __restrict__ vh,
    float*        __restrict__ rec,
    float*        __restrict__ part,
    float*        __restrict__ out)
{
    cg::grid_group gg = cg::this_grid();
    const int t = threadIdx.x;
    const int lane = t & 63, wv = t >> 6;
    const int nbx = gridDim.x;
    const int gw = blockIdx.x * 4 + wv, nwaves = nbx * 4;

    // ---------------- Phase 1: prep (one row per wave, grid-stride) --------
    for (int row = gw; row < VROWS; row += nwaves) {
        float4 us = make_float4(0.f, 0.f, 0.f, 0.f);
        float  nc = 0.f;
#pragma unroll
        for (int p = 0; p < 3; ++p) {
            const int e4 = lane + 64 * p;
            if (e4 < ROW_F4) {
                const float4 x = v4[(size_t)row * ROW_F4 + e4];
                const unsigned pk = enc4(x);
                const float4 xh = dec4(pk);
                vh[(size_t)row * ROW_U32 + e4] = pk;
                us.x += x.x; us.y += x.y; us.z += x.z; us.w += x.w;
                nc += (x.x*x.x - xh.x*xh.x) + (x.y*x.y - xh.y*xh.y)
                    + (x.z*x.z - xh.z*xh.z) + (x.w*x.w - xh.w*xh.w);
            } else if (e4 < ROW_U32) {
                vh[(size_t)row * ROW_U32 + e4] = 0u;
            }
        }
#pragma unroll
        for (int m = 4; m <= 32; m <<= 1) {
            us.x += __shfl_xor(us.x, m); us.y += __shfl_xor(us.y, m);
            us.z += __shfl_xor(us.z, m); us.w += __shfl_xor(us.w, m);
        }
        float* r = rec + (size_t)row * RECW;
        if (lane < 4) ((float4*)r)[lane] = us;
#pragma unroll
        for (int m = 1; m <= 32; m <<= 1) nc += __shfl_xor(nc, m);
        if (lane == 0) { r[16] = nc; r[17] = w[row]; }
    }

    gg.sync();

    // ---------------- Phase 2: sq gathers (XCD-pinned units) ---------------
    __shared__ int   vrow_s[SQ_RPB * NSPARSE];   //  832 B
    __shared__ float dsh   [SQ_RPB * NDENSE];    //  416 B
    __shared__ float4 vsh4 [NDENSE * 32];        // 6656 B

    const int xcd = blockIdx.x & 7;
    const int bix = blockIdx.x >> 3;
    const int bpx = nbx >> 3;
    const uint2* vh2 = (const uint2*)vh;

    const int kh  = lane & 1;            // k-half
    const int c   = (lane >> 1) & 7;     // field within slice
    const int h   = (lane >> 4) & 1;     // j-half
    const int rl2 = lane >> 5;           // row within wave

    for (int i = bix; i < UNITS_PER_XCD; i += bpx) {
        const int fid = xcd * UNITS_PER_XCD + i;
        const int slice = fid / SQ_CHUNKS, chunk = fid % SQ_CHUNKS;
        const int row0 = chunk * SQ_RPB;

        __syncthreads();
        for (int q = t; q < SQ_RPB * NSPARSE; q += 256) {
            const int r = q / NSPARSE, j = q % NSPARSE;
            vrow_s[q] = sparse[(row0 + r) * NSPARSE + j] + NDENSE + 1000 * j;
        }
        for (int q = t; q < SQ_RPB * NDENSE; q += 256)
            dsh[q] = dense[row0 * NDENSE + q];
        for (int q = t; q < NDENSE * 32; q += 256) {
            const int d = q >> 5, idx = q & 31;
            vsh4[q] = (32 * slice + idx < ROW_F4)
                      ? v4[(size_t)d * ROW_F4 + 32 * slice + idx]
                      : make_float4(0.f, 0.f, 0.f, 0.f);
        }
        __syncthreads();

        const int rloc = wv * 2 + rl2;    // 0..7

        // 13 independent 8 B gathers, forced resident (MLP)
        uint2 g[13];
#pragma unroll
        for (int jj = 0; jj < 13; ++jj) {
            const unsigned r = (unsigned)vrow_s[rloc * NSPARSE + h * 13 + jj];
            g[jj] = vh2[(size_t)r * ROW_U2 + slice * 16 + c * 2 + kh];
        }

        float a[8];
#pragma unroll
        for (int q = 0; q < 8; ++q) a[q] = 0.f;

        if (h == 0) {   // dense contribution once (exact fp32)
#pragma unroll
            for (int d = 0; d < NDENSE; ++d) {
                const float wg = dsh[rloc * NDENSE + d];
                const float4 b0 = vsh4[d * 32 + c * 4 + kh * 2];
                const float4 b1 = vsh4[d * 32 + c * 4 + kh * 2 + 1];
                a[0] += wg*b0.x; a[1] += wg*b0.y; a[2] += wg*b0.z; a[3] += wg*b0.w;
                a[4] += wg*b1.x; a[5] += wg*b1.y; a[6] += wg*b1.z; a[7] += wg*b1.w;
            }
        }

#pragma unroll
        for (int jj = 0; jj < 13; ++jj)
            asm volatile("" :: "v"(g[jj].x), "v"(g[jj].y));

#pragma unroll
        for (int jj = 0; jj < 13; ++jj) {
            const float4 d0 = dec4(g[jj].x), d1 = dec4(g[jj].y);
            a[0] += d0.x; a[1] += d0.y; a[2] += d0.z; a[3] += d0.w;
            a[4] += d1.x; a[5] += d1.y; a[6] += d1.z; a[7] += d1.w;
        }

        // fold j-halves
#pragma unroll
        for (int q = 0; q < 8; ++q) a[q] += __shfl_xor(a[q], 16);

        float sq = a[0]*a[0] + a[1]*a[1] + a[2]*a[2] + a[3]*a[3]
                 + a[4]*a[4] + a[5]*a[5] + a[6]*a[6] + a[7]*a[7];
        sq += __shfl_xor(sq, 1);
        sq += __shfl_xor(sq, 2);
        sq += __shfl_xor(sq, 4);
        sq += __shfl_xor(sq, 8);
        if ((lane & 31) == 0) part[slice * BATCH + row0 + rloc] = sq;
    }

    gg.sync();

    // ---------------- Phase 3: out (one row per wave, grid-stride) ---------
    for (int b = gw; b < BATCH; b += nwaves) {
        const int grp = lane >> 4, k = lane & 15;
        float s = 0.f;
        for (int j = grp; j < NSPARSE; j += 4) {
            const int r = sparse[b * NSPARSE + j] + NDENSE + 1000 * j;
            s += rec[(size_t)r * RECW + k];
        }
        for (int d = grp; d < NDENSE; d += 4)
            s += dense[b * NDENSE + d] * rec[(size_t)d * RECW + k];
        s += __shfl_xor(s, 16);
        s += __shfl_xor(s, 32);

        float s2 = s * s;
        s2 += __shfl_xor(s2, 1);
        s2 += __shfl_xor(s2, 2);
        s2 += __shfl_xor(s2, 4);
        s2 += __shfl_xor(s2, 8);

        float red = 0.f, fo = 0.f;
        if (lane < NSLICE) red = part[lane * BATCH + b];
        if (lane < NSPARSE) {
            const int r = sparse[b * NSPARSE + lane] + NDENSE + 1000 * lane;
            red += rec[(size_t)r * RECW + 16];
            fo   = rec[(size_t)r * RECW + 17];
        }
        if (lane < NDENSE) fo += dense[b * NDENSE + lane] * rec[(size_t)lane * RECW + 17];
#pragma unroll
        for (int m = 1; m <= 32; m <<= 1) {
            fo  += __shfl_xor(fo, m);
            red += __shfl_xor(red, m);
        }
        if (lane == 0) out[b] = w0[0] + fo + 0.5f * (s2 - red);
    }
}

// ---------------------------------------------------------------------------
// Fallback path: proven R9 three-kernel pipeline.
__global__ __launch_bounds__(256) void ffm_prep(
    const float4* __restrict__ v4, const float* __restrict__ w,
    unsigned* __restrict__ vh, float* __restrict__ rec)
{
    const int wv = threadIdx.x >> 6, lane = threadIdx.x & 63;
    const int row = blockIdx.x * 4 + wv;
    if (row >= VROWS) return;
    float4 us = make_float4(0.f, 0.f, 0.f, 0.f);
    float  nc = 0.f;
#pragma unroll
    for (int p = 0; p < 3; ++p) {
        const int e4 = lane + 64 * p;
        if (e4 < ROW_F4) {
            const float4 x = v4[(size_t)row * ROW_F4 + e4];
            const unsigned pk = enc4(x);
            const float4 xh = dec4(pk);
            vh[(size_t)row * ROW_U32 + e4] = pk;
            us.x += x.x; us.y += x.y; us.z += x.z; us.w += x.w;
            nc += (x.x*x.x - xh.x*xh.x) + (x.y*x.y - xh.y*xh.y)
                + (x.z*x.z - xh.z*xh.z) + (x.w*x.w - xh.w*xh.w);
        } else if (e4 < ROW_U32) {
            vh[(size_t)row * ROW_U32 + e4] = 0u;
        }
    }
#pragma unroll
    for (int m = 4; m <= 32; m <<= 1) {
        us.x += __shfl_xor(us.x, m); us.y += __shfl_xor(us.y, m);
        us.z += __shfl_xor(us.z, m); us.w += __shfl_xor(us.w, m);
    }
    float* r = rec + (size_t)row * RECW;
    if (lane < 4) ((float4*)r)[lane] = us;
#pragma unroll
    for (int m = 1; m <= 32; m <<= 1) nc += __shfl_xor(nc, m);
    if (lane == 0) { r[16] = nc; r[17] = w[row]; }
}

__global__ __launch_bounds__(256) void ffm_sq(
    const float* __restrict__ dense, const int* __restrict__ sparse,
    const float4* __restrict__ v4, const uint4* __restrict__ vh4,
    float* __restrict__ part)
{
    const int x = blockIdx.x & 7;
    const int i = blockIdx.x >> 3;
    const int fid = x * 80 + i;
    const int slice = fid >> 7, chunk = fid & 127;
    const int row0 = chunk * 32;

    __shared__ int    vrow_s[32 * NSPARSE];
    __shared__ float  dsh   [32 * NDENSE];
    __shared__ float4 vsh4  [NDENSE * 32];

    const int t = threadIdx.x;
    for (int q = t; q < 32 * NSPARSE; q += 256) {
        const int r = q / NSPARSE, j = q % NSPARSE;
        vrow_s[q] = sparse[(row0 + r) * NSPARSE + j] + NDENSE + 1000 * j;
    }
    for (int q = t; q < 32 * NDENSE; q += 256)
        dsh[q] = dense[row0 * NDENSE + q];
    for (int q = t; q < NDENSE * 32; q += 256) {
        const int d = q >> 5, idx = q & 31;
        vsh4[q] = (32 * slice + idx < ROW_F4)
                  ? v4[(size_t)d * ROW_F4 + 32 * slice + idx]
                  : make_float4(0.f, 0.f, 0.f, 0.f);
    }
    __syncthreads();

    const int lane = t & 63, wv = t >> 6;
    const int rl = wv * 8 + (lane >> 3);
    const int c  = lane & 7;

    float4 a0 = make_float4(0.f,0.f,0.f,0.f), a1 = a0, a2 = a0, a3 = a0;
#pragma unroll
    for (int d = 0; d < NDENSE; ++d) {
        const float wg = dsh[rl * NDENSE + d];
        const float4 b0 = vsh4[d * 32 + c * 4 + 0];
        const float4 b1 = vsh4[d * 32 + c * 4 + 1];
        const float4 b2 = vsh4[d * 32 + c * 4 + 2];
        const float4 b3 = vsh4[d * 32 + c * 4 + 3];
        a0.x += wg*b0.x; a0.y += wg*b0.y; a0.z += wg*b0.z; a0.w += wg*b0.w;
        a1.x += wg*b1.x; a1.y += wg*b1.y; a1.z += wg*b1.z; a1.w += wg*b1.w;
        a2.x += wg*b2.x; a2.y += wg*b2.y; a2.z += wg*b2.z; a2.w += wg*b2.w;
        a3.x += wg*b3.x; a3.y += wg*b3.y; a3.z += wg*b3.z; a3.w += wg*b3.w;
    }
#pragma unroll
    for (int j = 0; j < NSPARSE; ++j) {
        const unsigned r = (unsigned)vrow_s[rl * NSPARSE + j];
        const uint4 g = vh4[(size_t)r * ROW_U4 + slice * 8 + c];
        const float4 d0 = dec4(g.x), d1 = dec4(g.y), d2 = dec4(g.z), d3 = dec4(g.w);
        a0.x += d0.x; a0.y += d0.y; a0.z += d0.z; a0.w += d0.w;
        a1.x += d1.x; a1.y += d1.y; a1.z += d1.z; a1.w += d1.w;
        a2.x += d2.x; a2.y += d2.y; a2.z += d2.z; a2.w += d2.w;
        a3.x += d3.x; a3.y += d3.y; a3.z += d3.z; a3.w += d3.w;
    }
    float sq = a0.x*a0.x + a0.y*a0.y + a0.z*a0.z + a0.w*a0.w
             + a1.x*a1.x + a1.y*a1.y + a1.z*a1.z + a1.w*a1.w
             + a2.x*a2.x + a2.y*a2.y + a2.z*a2.z + a2.w*a2.w
             + a3.x*a3.x + a3.y*a3.y + a3.z*a3.z + a3.w*a3.w;
    sq += __shfl_xor(sq, 1);
    sq += __shfl_xor(sq, 2);
    sq += __shfl_xor(sq, 4);
    if (c == 0) part[slice * BATCH + row0 + rl] = sq;
}

__global__ __launch_bounds__(256) void ffm_out(
    const float* __restrict__ dense, const int* __restrict__ sparse,
    const float* __restrict__ w0, const float* __restrict__ rec,
    const float* __restrict__ part, float* __restrict__ out)
{
    const int wave = threadIdx.x >> 6;
    const int lane = threadIdx.x & 63;
    const int b = blockIdx.x * 4 + wave;
    const int grp = lane >> 4, k = lane & 15;

    float s = 0.f;
    for (int j = grp; j < NSPARSE; j += 4) {
        const int r = sparse[b * NSPARSE + j] + NDENSE + 1000 * j;
        s += rec[(size_t)r * RECW + k];
    }
    for (int d = grp; d < NDENSE; d += 4)
        s += dense[b * NDENSE + d] * rec[(size_t)d * RECW + k];
    s += __shfl_xor(s, 16);
    s += __shfl_xor(s, 32);

    float s2 = s * s;
    s2 += __shfl_xor(s2, 1);
    s2 += __shfl_xor(s2, 2);
    s2 += __shfl_xor(s2, 4);
    s2 += __shfl_xor(s2, 8);

    float red = 0.f, fo = 0.f;
    if (lane < NSLICE) red = part[lane * BATCH + b];
    if (lane < NSPARSE) {
        const int r = sparse[b * NSPARSE + lane] + NDENSE + 1000 * lane;
        red += rec[(size_t)r * RECW + 16];
        fo   = rec[(size_t)r * RECW + 17];
    }
    if (lane < NDENSE) fo += dense[b * NDENSE + lane] * rec[(size_t)lane * RECW + 17];
#pragma unroll
    for (int m = 1; m <= 32; m <<= 1) {
        fo  += __shfl_xor(fo, m);
        red += __shfl_xor(red, m);
    }
    if (lane == 0) out[b] = w0[0] + fo + 0.5f * (s2 - red);
}

__global__ __launch_bounds__(256) void ffm_fused(
    const float* __restrict__ dense, const int* __restrict__ sparse,
    const float* __restrict__ w0, const float* __restrict__ w,
    const float4* __restrict__ v4, float* __restrict__ out)
{
    const int wave = threadIdx.x >> 6;
    const int lane = threadIdx.x & 63;
    const int b = blockIdx.x * 4 + wave;

    float dv[NDENSE];
#pragma unroll
    for (int d = 0; d < NDENSE; ++d) dv[d] = dense[b * NDENSE + d];
    int myidx = 0;
    if (lane < NSPARSE) myidx = sparse[b * NSPARSE + lane] + NDENSE + 1000 * lane;

    float4 s = make_float4(0.f, 0.f, 0.f, 0.f);
    float  sq = 0.f;
#pragma unroll
    for (int p = 0; p < 3; ++p) {
        const int e4 = lane + 64 * p;
        if (e4 < ROW_F4) {
            float4 acc = make_float4(0.f, 0.f, 0.f, 0.f);
#pragma unroll
            for (int d = 0; d < NDENSE; ++d) {
                const float4 vv = v4[d * ROW_F4 + e4];
                acc.x += dv[d]*vv.x; acc.y += dv[d]*vv.y;
                acc.z += dv[d]*vv.z; acc.w += dv[d]*vv.w;
            }
#pragma unroll
            for (int j = 0; j < NSPARSE; ++j) {
                const int ij = __shfl(myidx, j);
                const float4 vv = v4[(size_t)ij * ROW_F4 + e4];
                acc.x += vv.x; acc.y += vv.y; acc.z += vv.z; acc.w += vv.w;
            }
            s.x += acc.x; s.y += acc.y; s.z += acc.z; s.w += acc.w;
            sq  += acc.x*acc.x + acc.y*acc.y + acc.z*acc.z + acc.w*acc.w;
        }
    }
#pragma unroll
    for (int m = 4; m <= 32; m <<= 1) {
        s.x += __shfl_xor(s.x, m); s.y += __shfl_xor(s.y, m);
        s.z += __shfl_xor(s.z, m); s.w += __shfl_xor(s.w, m);
    }
    float s2 = s.x*s.x + s.y*s.y + s.z*s.z + s.w*s.w;
    s2 += __shfl_xor(s2, 1);
    s2 += __shfl_xor(s2, 2);
#pragma unroll
    for (int m = 1; m <= 32; m <<= 1) sq += __shfl_xor(sq, m);
    float fo = 0.f;
    if (lane < NSPARSE) fo = w[myidx];
    if (lane < NDENSE)  fo += dense[b * NDENSE + lane] * w[lane];
#pragma unroll
    for (int m = 1; m <= 32; m <<= 1) fo += __shfl_xor(fo, m);
    if (lane == 0) out[b] = w0[0] + fo + 0.5f * (s2 - sq);
}

extern "C" void kernel_launch(void* const* d_in, const int* in_sizes, int n_in,
                              void* d_out, int out_size, void* d_ws, size_t ws_size,
                              hipStream_t stream) {
    const float*  dense  = (const float*)d_in[0];
    const int*    sparse = (const int*)d_in[1];
    const float*  w0     = (const float*)d_in[2];
    const float*  w      = (const float*)d_in[3];
    const float4* v4     = (const float4*)d_in[4];
    float* out = (float*)d_out;

    const size_t VH_B   = (size_t)VROWS * 640;                       // 16.65 MB
    const size_t RC_OFF = (VH_B + 255) & ~(size_t)255;
    const size_t RC_B   = (size_t)VROWS * RECW * 4;                  // 3.33 MB
    const size_t PT_OFF = (RC_OFF + RC_B + 255) & ~(size_t)255;
    const size_t PT_B   = (size_t)NSLICE * BATCH * 4;                // 80 KB

    if (ws_size >= PT_OFF + PT_B) {
        unsigned* vh  = (unsigned*)d_ws;
        float*    rc  = (float*)((char*)d_ws + RC_OFF);
        float*    prt = (float*)((char*)d_ws + PT_OFF);

        int nb = 0;
        hipError_t oe = hipOccupancyMaxActiveBlocksPerMultiprocessor(
            &nb, (const void*)ffm_coop, 256, 0);
        int grid = 2048;
        if (oe == hipSuccess && nb > 0) {
            int cap = nb * 256;           // 256 CUs
            if (cap < grid) grid = cap;
        }
        grid &= ~7;
        if (grid < 8) grid = 8;

        void* args[] = { (void*)&dense, (void*)&sparse, (void*)&w0, (void*)&w,
                         (void*)&v4, (void*)&vh, (void*)&rc, (void*)&prt,
                         (void*)&out };
        hipError_t le = hipLaunchCooperativeKernel(
            (const void*)ffm_coop, dim3(grid), dim3(256), args, 0, stream);

        if (le != hipSuccess) {
            // Fallback: proven R9 three-kernel pipeline.
            hipLaunchKernelGGL(ffm_prep, dim3((VROWS + 3) / 4), dim3(256), 0, stream,
                               v4, w, vh, rc);
            hipLaunchKernelGGL(ffm_sq, dim3(8 * 80), dim3(256), 0, stream,
                               dense, sparse, v4, (const uint4*)vh, prt);
            hipLaunchKernelGGL(ffm_out, dim3(BATCH / 4), dim3(256), 0, stream,
                               dense, sparse, w0, rc, prt, out);
        }
    } else {
        hipLaunchKernelGGL(ffm_fused, dim3(BATCH / 4), dim3(256), 0, stream,
                           dense, sparse, w0, w, v4, out);
    }
}

// Round 12
// 47.261 us; speedup vs baseline: 5.8410x; 5.8410x over previous
//
#include <hip/hip_runtime.h>

#define NDENSE 13
#define NSPARSE 26
#define ROW_F4 156     // fp32 v row = 156 float4
#define BATCH 4096
#define VROWS 26013
#define ROW_U32 160    // padded f8 row = 160 uint32 = 640 B (5 x 128B lines)
#define ROW_U4  40     // f8 row = 40 uint4; uint4 c = field c (16 f8 = full field)
#define RECW   32      // packed row record: u[16], nrmc, w, pad -> 128 B
#define PREP1B 6504    // ceil(26013/4) blocks for prep1
#define PREP2B 256     // dense-GEMM blocks (16 batch rows each)

// ---------------- fp8 e4m3 (OCP) encode/decode --------------------------
#if defined(__has_builtin)
#if __has_builtin(__builtin_amdgcn_cvt_pk_fp8_f32) && __has_builtin(__builtin_amdgcn_cvt_pk_f32_fp8)
#define FP8_HW 1
#endif
#endif

typedef float f32x2 __attribute__((ext_vector_type(2)));

__device__ inline unsigned enc1(float f) {
    unsigned u = __float_as_uint(f);
    unsigned s = (u >> 24) & 0x80u;
    unsigned a = u & 0x7fffffffu;
    if (a >= 0x3c800000u) {
        unsigned r = a + 0x7ffffu + ((a >> 20) & 1u);
        return s | ((r - (120u << 23)) >> 20);
    }
    return s | (unsigned)__float2uint_rn(__uint_as_float(a) * 512.f);
}
__device__ inline float dec1(unsigned b) {
    unsigned em = b & 0x7fu;
    float mag = (em >= 8u) ? __uint_as_float((em << 20) + (120u << 23))
                           : (float)em * 0x1p-9f;
    return (b & 0x80u) ? -mag : mag;
}
__device__ inline unsigned enc4(float4 x) {
#ifdef FP8_HW
    int pk = 0;
    pk = __builtin_amdgcn_cvt_pk_fp8_f32(x.x, x.y, pk, false);
    pk = __builtin_amdgcn_cvt_pk_fp8_f32(x.z, x.w, pk, true);
    return (unsigned)pk;
#else
    return enc1(x.x) | (enc1(x.y) << 8) | (enc1(x.z) << 16) | (enc1(x.w) << 24);
#endif
}
__device__ inline float4 dec4(unsigned p) {
#ifdef FP8_HW
    f32x2 lo = __builtin_amdgcn_cvt_pk_f32_fp8((int)p, false);
    f32x2 hi = __builtin_amdgcn_cvt_pk_f32_fp8((int)p, true);
    return make_float4(lo.x, lo.y, hi.x, hi.y);
#else
    return make_float4(dec1(p & 0xffu), dec1((p >> 8) & 0xffu),
                       dec1((p >> 16) & 0xffu), dec1((p >> 24) & 0xffu));
#endif
}

// ---------------------------------------------------------------------------
// Prep (combined): blocks [0, PREP1B): f8 table + packed records.
//                  blocks [PREP1B, PREP1B+PREP2B): DV = dense @ v[:13] (exact).
__global__ __launch_bounds__(256) void ffm_prep(
    const float*  __restrict__ dense,
    const float4* __restrict__ v4,
    const float*  __restrict__ w,
    unsigned*     __restrict__ vh,
    float*        __restrict__ rec,
    float4*       __restrict__ dv)      // [4096*156]
{
    __shared__ float4 vsh4[NDENSE * ROW_F4];   // 32448 B (prep2 only)
    __shared__ float  dsh [16 * NDENSE];

    const int t = threadIdx.x;
    if (blockIdx.x < PREP1B) {
        // ---- prep1: per-v-row f8 encode + u/nrmc/w record ----
        const int wv = t >> 6, lane = t & 63;
        const int row = blockIdx.x * 4 + wv;
        if (row >= VROWS) return;

        float4 us = make_float4(0.f, 0.f, 0.f, 0.f);
        float  nc = 0.f;
#pragma unroll
        for (int p = 0; p < 3; ++p) {
            const int e4 = lane + 64 * p;
            if (e4 < ROW_F4) {
                const float4 x = v4[(size_t)row * ROW_F4 + e4];
                const unsigned pk = enc4(x);
                const float4 xh = dec4(pk);
                vh[(size_t)row * ROW_U32 + e4] = pk;
                us.x += x.x; us.y += x.y; us.z += x.z; us.w += x.w;
                nc += (x.x*x.x - xh.x*xh.x) + (x.y*x.y - xh.y*xh.y)
                    + (x.z*x.z - xh.z*xh.z) + (x.w*x.w - xh.w*xh.w);
            } else if (e4 < ROW_U32) {
                vh[(size_t)row * ROW_U32 + e4] = 0u;
            }
        }
#pragma unroll
        for (int m = 4; m <= 32; m <<= 1) {
            us.x += __shfl_xor(us.x, m); us.y += __shfl_xor(us.y, m);
            us.z += __shfl_xor(us.z, m); us.w += __shfl_xor(us.w, m);
        }
        float* r = rec + (size_t)row * RECW;
        if (lane < 4) ((float4*)r)[lane] = us;
#pragma unroll
        for (int m = 1; m <= 32; m <<= 1) nc += __shfl_xor(nc, m);
        if (lane == 0) { r[16] = nc; r[17] = w[row]; }
    } else {
        // ---- prep2: DV[b] = sum_d dense[b,d] * v[d]  (16 rows/block) ----
        const int pb = blockIdx.x - PREP1B;
        const int row0 = pb * 16;
        for (int q = t; q < NDENSE * ROW_F4; q += 256) vsh4[q] = v4[q];
        for (int q = t; q < 16 * NDENSE; q += 256)
            dsh[q] = dense[row0 * NDENSE + q];
        __syncthreads();

        const int r = t >> 4, q0 = t & 15;
        float dl[NDENSE];
#pragma unroll
        for (int d = 0; d < NDENSE; ++d) dl[d] = dsh[r * NDENSE + d];

        for (int e = q0; e < ROW_F4; e += 16) {
            float4 a = make_float4(0.f, 0.f, 0.f, 0.f);
#pragma unroll
            for (int d = 0; d < NDENSE; ++d) {
                const float4 vv = vsh4[d * ROW_F4 + e];
                a.x += dl[d]*vv.x; a.y += dl[d]*vv.y;
                a.z += dl[d]*vv.z; a.w += dl[d]*vv.w;
            }
            dv[(size_t)(row0 + r) * ROW_F4 + e] = a;
        }
    }
}

// ---------------------------------------------------------------------------
// sq kernel: wave = one batch row. Each of the 26 gathers reads one CONTIGUOUS
// 640 B f8 row (lanes 0..39, uint4 = one full 16-dim field vector). acc[16]
// per lane = its field; DV (exact fp32 dense part) pre-loaded into acc.
// Two 13-deep load batches for MLP. One sq partial per b.
__global__ __launch_bounds__(256) void ffm_sq(
    const int*    __restrict__ sparse,
    const uint4*  __restrict__ vh4,
    const float4* __restrict__ dv,
    float*        __restrict__ part)    // [4096]
{
    const int t = threadIdx.x;
    const int wv = t >> 6, lane = t & 63;
    const int b = blockIdx.x * 4 + wv;
    const bool act = lane < 39;         // lane = field index

    int myidx = 0;
    if (lane < NSPARSE) myidx = sparse[b * NSPARSE + lane] + NDENSE + 1000 * lane;

    // acc[16] = exact fp32 dense contribution for this lane's field
    float acc[16];
    {
        float4 a0 = make_float4(0.f,0.f,0.f,0.f), a1 = a0, a2 = a0, a3 = a0;
        if (act) {
            const float4* p = dv + (size_t)b * ROW_F4 + lane * 4;
            a0 = p[0]; a1 = p[1]; a2 = p[2]; a3 = p[3];
        }
        acc[0]=a0.x; acc[1]=a0.y; acc[2]=a0.z; acc[3]=a0.w;
        acc[4]=a1.x; acc[5]=a1.y; acc[6]=a1.z; acc[7]=a1.w;
        acc[8]=a2.x; acc[9]=a2.y; acc[10]=a2.z; acc[11]=a2.w;
        acc[12]=a3.x; acc[13]=a3.y; acc[14]=a3.z; acc[15]=a3.w;
    }

    // 26 gathers in two 13-deep batches (MLP); each instr reads 640 B contiguous
#pragma unroll
    for (int half = 0; half < 2; ++half) {
        uint4 g[13];
#pragma unroll
        for (int jj = 0; jj < 13; ++jj) {
            const unsigned r = (unsigned)__shfl(myidx, half * 13 + jj);
            g[jj] = act ? vh4[(size_t)r * ROW_U4 + lane]
                        : make_uint4(0u, 0u, 0u, 0u);
        }
#pragma unroll
        for (int jj = 0; jj < 13; ++jj)
            asm volatile("" :: "v"(g[jj].x), "v"(g[jj].y),
                             "v"(g[jj].z), "v"(g[jj].w));
#pragma unroll
        for (int jj = 0; jj < 13; ++jj) {
            const float4 d0 = dec4(g[jj].x), d1 = dec4(g[jj].y),
                         d2 = dec4(g[jj].z), d3 = dec4(g[jj].w);
            acc[0]+=d0.x; acc[1]+=d0.y; acc[2]+=d0.z; acc[3]+=d0.w;
            acc[4]+=d1.x; acc[5]+=d1.y; acc[6]+=d1.z; acc[7]+=d1.w;
            acc[8]+=d2.x; acc[9]+=d2.y; acc[10]+=d2.z; acc[11]+=d2.w;
            acc[12]+=d3.x; acc[13]+=d3.y; acc[14]+=d3.z; acc[15]+=d3.w;
        }
    }

    float sq = 0.f;
#pragma unroll
    for (int q = 0; q < 16; ++q) sq += acc[q] * acc[q];
#pragma unroll
    for (int m = 1; m <= 32; m <<= 1) sq += __shfl_xor(sq, m);
    if (lane == 0) part[b] = sq;
}

// ---------------------------------------------------------------------------
// Final: exact s from packed records, sq = partial + diagonal correction,
// first order. One wave per batch row.
__global__ __launch_bounds__(256) void ffm_out(
    const float* __restrict__ dense,
    const int*   __restrict__ sparse,
    const float* __restrict__ w0,
    const float* __restrict__ rec,
    const float* __restrict__ part,
    float*       __restrict__ out)
{
    const int wave = threadIdx.x >> 6;
    const int lane = threadIdx.x & 63;
    const int b = blockIdx.x * 4 + wave;
    const int grp = lane >> 4, k = lane & 15;

    float s = 0.f;
    for (int j = grp; j < NSPARSE; j += 4) {
        const int r = sparse[b * NSPARSE + j] + NDENSE + 1000 * j;
        s += rec[(size_t)r * RECW + k];
    }
    for (int d = grp; d < NDENSE; d += 4)
        s += dense[b * NDENSE + d] * rec[(size_t)d * RECW + k];
    s += __shfl_xor(s, 16);
    s += __shfl_xor(s, 32);

    float s2 = s * s;
    s2 += __shfl_xor(s2, 1);
    s2 += __shfl_xor(s2, 2);
    s2 += __shfl_xor(s2, 4);
    s2 += __shfl_xor(s2, 8);

    float red = 0.f, fo = 0.f;
    if (lane == 0) red = part[b];
    if (lane < NSPARSE) {
        const int r = sparse[b * NSPARSE + lane] + NDENSE + 1000 * lane;
        red += rec[(size_t)r * RECW + 16];
        fo   = rec[(size_t)r * RECW + 17];
    }
    if (lane < NDENSE) fo += dense[b * NDENSE + lane] * rec[(size_t)lane * RECW + 17];
#pragma unroll
    for (int m = 1; m <= 32; m <<= 1) {
        fo  += __shfl_xor(fo, m);
        red += __shfl_xor(red, m);
    }
    if (lane == 0) out[b] = w0[0] + fo + 0.5f * (s2 - red);
}

// ---------------------------------------------------------------------------
// Fallback: R1 fused kernel (only if ws too small).
__global__ __launch_bounds__(256) void ffm_fused(
    const float* __restrict__ dense, const int* __restrict__ sparse,
    const float* __restrict__ w0, const float* __restrict__ w,
    const float4* __restrict__ v4, float* __restrict__ out)
{
    const int wave = threadIdx.x >> 6;
    const int lane = threadIdx.x & 63;
    const int b = blockIdx.x * 4 + wave;

    float dvv[NDENSE];
#pragma unroll
    for (int d = 0; d < NDENSE; ++d) dvv[d] = dense[b * NDENSE + d];
    int myidx = 0;
    if (lane < NSPARSE) myidx = sparse[b * NSPARSE + lane] + NDENSE + 1000 * lane;

    float4 s = make_float4(0.f, 0.f, 0.f, 0.f);
    float  sq = 0.f;
#pragma unroll
    for (int p = 0; p < 3; ++p) {
        const int e4 = lane + 64 * p;
        if (e4 < ROW_F4) {
            float4 acc = make_float4(0.f, 0.f, 0.f, 0.f);
#pragma unroll
            for (int d = 0; d < NDENSE; ++d) {
                const float4 vv = v4[d * ROW_F4 + e4];
                acc.x += dvv[d]*vv.x; acc.y += dvv[d]*vv.y;
                acc.z += dvv[d]*vv.z; acc.w += dvv[d]*vv.w;
            }
#pragma unroll
            for (int j = 0; j < NSPARSE; ++j) {
                const int ij = __shfl(myidx, j);
                const float4 vv = v4[(size_t)ij * ROW_F4 + e4];
                acc.x += vv.x; acc.y += vv.y; acc.z += vv.z; acc.w += vv.w;
            }
            s.x += acc.x; s.y += acc.y; s.z += acc.z; s.w += acc.w;
            sq  += acc.x*acc.x + acc.y*acc.y + acc.z*acc.z + acc.w*acc.w;
        }
    }
#pragma unroll
    for (int m = 4; m <= 32; m <<= 1) {
        s.x += __shfl_xor(s.x, m); s.y += __shfl_xor(s.y, m);
        s.z += __shfl_xor(s.z, m); s.w += __shfl_xor(s.w, m);
    }
    float s2 = s.x*s.x + s.y*s.y + s.z*s.z + s.w*s.w;
    s2 += __shfl_xor(s2, 1);
    s2 += __shfl_xor(s2, 2);
#pragma unroll
    for (int m = 1; m <= 32; m <<= 1) sq += __shfl_xor(sq, m);
    float fo = 0.f;
    if (lane < NSPARSE) fo = w[myidx];
    if (lane < NDENSE)  fo += dense[b * NDENSE + lane] * w[lane];
#pragma unroll
    for (int m = 1; m <= 32; m <<= 1) fo += __shfl_xor(fo, m);
    if (lane == 0) out[b] = w0[0] + fo + 0.5f * (s2 - sq);
}

extern "C" void kernel_launch(void* const* d_in, const int* in_sizes, int n_in,
                              void* d_out, int out_size, void* d_ws, size_t ws_size,
                              hipStream_t stream) {
    const float*  dense  = (const float*)d_in[0];
    const int*    sparse = (const int*)d_in[1];
    const float*  w0     = (const float*)d_in[2];
    const float*  w      = (const float*)d_in[3];
    const float4* v4     = (const float4*)d_in[4];
    float* out = (float*)d_out;

    const size_t VH_B   = (size_t)VROWS * 640;                       // 16.65 MB
    const size_t RC_OFF = (VH_B + 255) & ~(size_t)255;
    const size_t RC_B   = (size_t)VROWS * RECW * 4;                  // 3.33 MB
    const size_t DV_OFF = (RC_OFF + RC_B + 255) & ~(size_t)255;
    const size_t DV_B   = (size_t)BATCH * ROW_F4 * 16;               // 10.22 MB
    const size_t PT_OFF = (DV_OFF + DV_B + 255) & ~(size_t)255;
    const size_t PT_B   = (size_t)BATCH * 4;                         // 16 KB

    if (ws_size >= PT_OFF + PT_B) {
        unsigned* vh  = (unsigned*)d_ws;
        float*    rc  = (float*)((char*)d_ws + RC_OFF);
        float4*   dvp = (float4*)((char*)d_ws + DV_OFF);
        float*    prt = (float*)((char*)d_ws + PT_OFF);

        hipLaunchKernelGGL(ffm_prep, dim3(PREP1B + PREP2B), dim3(256), 0, stream,
                           dense, v4, w, vh, rc, dvp);
        hipLaunchKernelGGL(ffm_sq, dim3(BATCH / 4), dim3(256), 0, stream,
                           sparse, (const uint4*)vh, dvp, prt);
        hipLaunchKernelGGL(ffm_out, dim3(BATCH / 4), dim3(256), 0, stream,
                           dense, sparse, w0, rc, prt, out);
    } else {
        hipLaunchKernelGGL(ffm_fused, dim3(BATCH / 4), dim3(256), 0, stream,
                           dense, sparse, w0, w, v4, out);
    }
}

// Round 13
// 38.041 us; speedup vs baseline: 7.2567x; 1.2424x over previous
//
#include <hip/hip_runtime.h>

#define NDENSE 13
#define NSPARSE 26
#define ROW_F4 156     // fp32 v row = 156 float4
#define BATCH 4096
#define VROWS 26013
#define ROW_U32 160    // padded f8 row = 160 uint32 = 640 B = 5 x 128B slices
#define ROW_U4  40     // = 40 uint4
#define NSLICE 5       // 128 B f8 slices per row (8 fields each, slice 4 has 7+pad)
#define SRPB   32      // rows per block in sq kernel
#define RECW   32      // floats per packed row record: u[16], nrmc, w, pad -> 128 B

// ---------------- fp8 e4m3 (OCP) encode/decode --------------------------
#if defined(__has_builtin)
#if __has_builtin(__builtin_amdgcn_cvt_pk_fp8_f32) && __has_builtin(__builtin_amdgcn_cvt_pk_f32_fp8)
#define FP8_HW 1
#endif
#endif

typedef float f32x2 __attribute__((ext_vector_type(2)));

__device__ inline unsigned enc1(float f) {
    unsigned u = __float_as_uint(f);
    unsigned s = (u >> 24) & 0x80u;
    unsigned a = u & 0x7fffffffu;
    if (a >= 0x3c800000u) {                       // |f| >= 2^-6 : normal
        unsigned r = a + 0x7ffffu + ((a >> 20) & 1u);   // RNE at bit 20
        return s | ((r - (120u << 23)) >> 20);
    }
    return s | (unsigned)__float2uint_rn(__uint_as_float(a) * 512.f); // subnormal
}
__device__ inline float dec1(unsigned b) {
    unsigned em = b & 0x7fu;
    float mag = (em >= 8u) ? __uint_as_float((em << 20) + (120u << 23))
                           : (float)em * 0x1p-9f;
    return (b & 0x80u) ? -mag : mag;
}
__device__ inline unsigned enc4(float4 x) {
#ifdef FP8_HW
    int pk = 0;
    pk = __builtin_amdgcn_cvt_pk_fp8_f32(x.x, x.y, pk, false);
    pk = __builtin_amdgcn_cvt_pk_fp8_f32(x.z, x.w, pk, true);
    return (unsigned)pk;
#else
    return enc1(x.x) | (enc1(x.y) << 8) | (enc1(x.z) << 16) | (enc1(x.w) << 24);
#endif
}
__device__ inline float4 dec4(unsigned p) {
#ifdef FP8_HW
    f32x2 lo = __builtin_amdgcn_cvt_pk_f32_fp8((int)p, false);
    f32x2 hi = __builtin_amdgcn_cvt_pk_f32_fp8((int)p, true);
    return make_float4(lo.x, lo.y, hi.x, hi.y);
#else
    return make_float4(dec1(p & 0xffu), dec1((p >> 8) & 0xffu),
                       dec1((p >> 16) & 0xffu), dec1((p >> 24) & 0xffu));
#endif
}

// ---------------------------------------------------------------------------
// Prep: one pass over v. Emits (a) f8 copy (640 B rows, zero pad), (b) packed
// 128 B record per row: u[16] = sum_f v[r,f,:], nrmc = ||v||^2-||f8||^2, w[r].
__global__ __launch_bounds__(256) void ffm_prep(
    const float4* __restrict__ v4, const float* __restrict__ w,
    unsigned* __restrict__ vh, float* __restrict__ rec)
{
    const int wv = threadIdx.x >> 6, lane = threadIdx.x & 63;
    const int row = blockIdx.x * 4 + wv;
    if (row >= VROWS) return;

    float4 us = make_float4(0.f, 0.f, 0.f, 0.f);
    float  nc = 0.f;
#pragma unroll
    for (int p = 0; p < 3; ++p) {
        const int e4 = lane + 64 * p;
        if (e4 < ROW_F4) {
            const float4 x = v4[(size_t)row * ROW_F4 + e4];
            const unsigned pk = enc4(x);
            const float4 xh = dec4(pk);
            vh[(size_t)row * ROW_U32 + e4] = pk;
            us.x += x.x; us.y += x.y; us.z += x.z; us.w += x.w;
            nc += (x.x*x.x - xh.x*xh.x) + (x.y*x.y - xh.y*xh.y)
                + (x.z*x.z - xh.z*xh.z) + (x.w*x.w - xh.w*xh.w);
        } else if (e4 < ROW_U32) {
            vh[(size_t)row * ROW_U32 + e4] = 0u;   // pad = 0
        }
    }
    // k-group = e4&3 = lane&3 (invariant under +64)
#pragma unroll
    for (int m = 4; m <= 32; m <<= 1) {
        us.x += __shfl_xor(us.x, m); us.y += __shfl_xor(us.y, m);
        us.z += __shfl_xor(us.z, m); us.w += __shfl_xor(us.w, m);
    }
    float* r = rec + (size_t)row * RECW;
    if (lane < 4) ((float4*)r)[lane] = us;
#pragma unroll
    for (int m = 1; m <= 32; m <<= 1) nc += __shfl_xor(nc, m);
    if (lane == 0) { r[16] = nc; r[17] = w[row]; }
}

// ---------------------------------------------------------------------------
// sq kernel: 128 B f8 slices (line-exact), XCD-pinned (<=2 slices/XCD).
// Slice s covers fields 8s..8s+7; lane owns (row, one field vector = 16 B).
// Dense contribution exact fp32 from LDS. Writes per-slice sq partials.
__global__ __launch_bounds__(256) void ffm_sq(
    const float* __restrict__ dense,
    const int*   __restrict__ sparse,
    const float4* __restrict__ v4,
    const uint4* __restrict__ vh4,
    float*       __restrict__ part)     // [5][4096]
{
    const int x = blockIdx.x & 7;
    const int i = blockIdx.x >> 3;       // 0..79 per XCD
    const int fid = x * 80 + i;          // 0..639
    const int slice = fid >> 7, chunk = fid & 127;
    const int row0 = chunk * SRPB;

    __shared__ int    vrow_s[SRPB * NSPARSE];  // 3328 B
    __shared__ float  dsh   [SRPB * NDENSE];   // 1664 B
    __shared__ float4 vsh4  [NDENSE * 32];     // 6656 B fp32 dense v-slice

    const int t = threadIdx.x;
    for (int q = t; q < SRPB * NSPARSE; q += 256) {
        const int r = q / NSPARSE, j = q % NSPARSE;
        vrow_s[q] = sparse[(row0 + r) * NSPARSE + j] + NDENSE + 1000 * j;
    }
    for (int q = t; q < SRPB * NDENSE; q += 256)
        dsh[q] = dense[row0 * NDENSE + q];
    for (int q = t; q < NDENSE * 32; q += 256) {
        const int d = q >> 5, idx = q & 31;          // f4 col = 32*slice + idx
        vsh4[q] = (32 * slice + idx < ROW_F4)
                  ? v4[(size_t)d * ROW_F4 + 32 * slice + idx]
                  : make_float4(0.f, 0.f, 0.f, 0.f);
    }
    __syncthreads();

    const int lane = t & 63, wv = t >> 6;
    const int rl = wv * 8 + (lane >> 3);   // local row 0..31
    const int c  = lane & 7;               // field within slice

    float4 a0 = make_float4(0.f,0.f,0.f,0.f), a1 = a0, a2 = a0, a3 = a0;

    // dense contribution (exact fp32): field 8*slice + c
#pragma unroll
    for (int d = 0; d < NDENSE; ++d) {
        const float wg = dsh[rl * NDENSE + d];
        const float4 b0 = vsh4[d * 32 + c * 4 + 0];
        const float4 b1 = vsh4[d * 32 + c * 4 + 1];
        const float4 b2 = vsh4[d * 32 + c * 4 + 2];
        const float4 b3 = vsh4[d * 32 + c * 4 + 3];
        a0.x += wg*b0.x; a0.y += wg*b0.y; a0.z += wg*b0.z; a0.w += wg*b0.w;
        a1.x += wg*b1.x; a1.y += wg*b1.y; a1.z += wg*b1.z; a1.w += wg*b1.w;
        a2.x += wg*b2.x; a2.y += wg*b2.y; a2.z += wg*b2.z; a2.w += wg*b2.w;
        a3.x += wg*b3.x; a3.y += wg*b3.y; a3.z += wg*b3.z; a3.w += wg*b3.w;
    }

    // 26 f8 gathers: 16 B each = one complete field vector (8 lanes = 128 B line)
#pragma unroll
    for (int j = 0; j < NSPARSE; ++j) {
        const unsigned r = (unsigned)vrow_s[rl * NSPARSE + j];
        const uint4 g = vh4[(size_t)r * ROW_U4 + slice * 8 + c];
        const float4 d0 = dec4(g.x), d1 = dec4(g.y), d2 = dec4(g.z), d3 = dec4(g.w);
        a0.x += d0.x; a0.y += d0.y; a0.z += d0.z; a0.w += d0.w;
        a1.x += d1.x; a1.y += d1.y; a1.z += d1.z; a1.w += d1.w;
        a2.x += d2.x; a2.y += d2.y; a2.z += d2.z; a2.w += d2.w;
        a3.x += d3.x; a3.y += d3.y; a3.z += d3.z; a3.w += d3.w;
    }

    float sq = a0.x*a0.x + a0.y*a0.y + a0.z*a0.z + a0.w*a0.w
             + a1.x*a1.x + a1.y*a1.y + a1.z*a1.z + a1.w*a1.w
             + a2.x*a2.x + a2.y*a2.y + a2.z*a2.z + a2.w*a2.w
             + a3.x*a3.x + a3.y*a3.y + a3.z*a3.z + a3.w*a3.w;
    sq += __shfl_xor(sq, 1);
    sq += __shfl_xor(sq, 2);
    sq += __shfl_xor(sq, 4);
    if (c == 0) part[slice * BATCH + row0 + rl] = sq;
}

// ---------------------------------------------------------------------------
// Final: exact s from packed records (1 line per gather), sq = partials +
// diagonal correction, first order. One wave per batch row.
__global__ __launch_bounds__(256) void ffm_out(
    const float* __restrict__ dense,
    const int*   __restrict__ sparse,
    const float* __restrict__ w0,
    const float* __restrict__ rec,
    const float* __restrict__ part,
    float*       __restrict__ out)
{
    const int wave = threadIdx.x >> 6;
    const int lane = threadIdx.x & 63;
    const int b = blockIdx.x * 4 + wave;
    const int g = lane >> 4, k = lane & 15;

    // exact first moment s[k]
    float s = 0.f;
    for (int j = g; j < NSPARSE; j += 4) {
        const int r = sparse[b * NSPARSE + j] + NDENSE + 1000 * j;
        s += rec[(size_t)r * RECW + k];
    }
    for (int d = g; d < NDENSE; d += 4)
        s += dense[b * NDENSE + d] * rec[(size_t)d * RECW + k];
    s += __shfl_xor(s, 16);
    s += __shfl_xor(s, 32);          // lanes with same k hold total s[k]

    float s2 = s * s;
    s2 += __shfl_xor(s2, 1);
    s2 += __shfl_xor(s2, 2);
    s2 += __shfl_xor(s2, 4);
    s2 += __shfl_xor(s2, 8);         // ||s||^2 in every lane

    float red = 0.f, fo = 0.f;
    if (lane < NSLICE) red = part[lane * BATCH + b];
    if (lane < NSPARSE) {
        const int r = sparse[b * NSPARSE + lane] + NDENSE + 1000 * lane;
        red += rec[(size_t)r * RECW + 16];   // diagonal correction (same line as u)
        fo   = rec[(size_t)r * RECW + 17];   // w[r] (same line)
    }
    if (lane < NDENSE) fo += dense[b * NDENSE + lane] * rec[(size_t)lane * RECW + 17];
#pragma unroll
    for (int m = 1; m <= 32; m <<= 1) {
        fo  += __shfl_xor(fo, m);
        red += __shfl_xor(red, m);
    }
    if (lane == 0) out[b] = w0[0] + fo + 0.5f * (s2 - red);
}

// ---------------------------------------------------------------------------
// Fallback: R1 fused kernel (only if ws too small).
__global__ __launch_bounds__(256) void ffm_fused(
    const float* __restrict__ dense, const int* __restrict__ sparse,
    const float* __restrict__ w0, const float* __restrict__ w,
    const float4* __restrict__ v4, float* __restrict__ out)
{
    const int wave = threadIdx.x >> 6;
    const int lane = threadIdx.x & 63;
    const int b = blockIdx.x * 4 + wave;

    float dv[NDENSE];
#pragma unroll
    for (int d = 0; d < NDENSE; ++d) dv[d] = dense[b * NDENSE + d];
    int myidx = 0;
    if (lane < NSPARSE) myidx = sparse[b * NSPARSE + lane] + NDENSE + 1000 * lane;

    float4 s = make_float4(0.f, 0.f, 0.f, 0.f);
    float  sq = 0.f;
#pragma unroll
    for (int p = 0; p < 3; ++p) {
        const int e4 = lane + 64 * p;
        if (e4 < ROW_F4) {
            float4 acc = make_float4(0.f, 0.f, 0.f, 0.f);
#pragma unroll
            for (int d = 0; d < NDENSE; ++d) {
                const float4 vv = v4[d * ROW_F4 + e4];
                acc.x += dv[d]*vv.x; acc.y += dv[d]*vv.y;
                acc.z += dv[d]*vv.z; acc.w += dv[d]*vv.w;
            }
#pragma unroll
            for (int j = 0; j < NSPARSE; ++j) {
                const int ij = __shfl(myidx, j);
                const float4 vv = v4[(size_t)ij * ROW_F4 + e4];
                acc.x += vv.x; acc.y += vv.y; acc.z += vv.z; acc.w += vv.w;
            }
            s.x += acc.x; s.y += acc.y; s.z += acc.z; s.w += acc.w;
            sq  += acc.x*acc.x + acc.y*acc.y + acc.z*acc.z + acc.w*acc.w;
        }
    }
#pragma unroll
    for (int m = 4; m <= 32; m <<= 1) {
        s.x += __shfl_xor(s.x, m); s.y += __shfl_xor(s.y, m);
        s.z += __shfl_xor(s.z, m); s.w += __shfl_xor(s.w, m);
    }
    float s2 = s.x*s.x + s.y*s.y + s.z*s.z + s.w*s.w;
    s2 += __shfl_xor(s2, 1);
    s2 += __shfl_xor(s2, 2);
#pragma unroll
    for (int m = 1; m <= 32; m <<= 1) sq += __shfl_xor(sq, m);
    float fo = 0.f;
    if (lane < NSPARSE) fo = w[myidx];
    if (lane < NDENSE)  fo += dense[b * NDENSE + lane] * w[lane];
#pragma unroll
    for (int m = 1; m <= 32; m <<= 1) fo += __shfl_xor(fo, m);
    if (lane == 0) out[b] = w0[0] + fo + 0.5f * (s2 - sq);
}

extern "C" void kernel_launch(void* const* d_in, const int* in_sizes, int n_in,
                              void* d_out, int out_size, void* d_ws, size_t ws_size,
                              hipStream_t stream) {
    const float*  dense  = (const float*)d_in[0];
    const int*    sparse = (const int*)d_in[1];
    const float*  w0     = (const float*)d_in[2];
    const float*  w      = (const float*)d_in[3];
    const float4* v4     = (const float4*)d_in[4];
    float* out = (float*)d_out;

    const size_t VH_B   = (size_t)VROWS * 640;                       // 16.65 MB
    const size_t RC_OFF = (VH_B + 255) & ~(size_t)255;
    const size_t RC_B   = (size_t)VROWS * RECW * 4;                  // 3.33 MB
    const size_t PT_OFF = (RC_OFF + RC_B + 255) & ~(size_t)255;
    const size_t PT_B   = (size_t)NSLICE * BATCH * 4;                // 80 KB

    if (ws_size >= PT_OFF + PT_B) {
        unsigned* vh  = (unsigned*)d_ws;
        float*    rc  = (float*)((char*)d_ws + RC_OFF);
        float*    prt = (float*)((char*)d_ws + PT_OFF);

        hipLaunchKernelGGL(ffm_prep, dim3((VROWS + 3) / 4), dim3(256), 0, stream,
                           v4, w, vh, rc);
        hipLaunchKernelGGL(ffm_sq, dim3(8 * 80), dim3(256), 0, stream,
                           dense, sparse, v4, (const uint4*)vh, prt);
        hipLaunchKernelGGL(ffm_out, dim3(BATCH / 4), dim3(256), 0, stream,
                           dense, sparse, w0, rc, prt, out);
    } else {
        hipLaunchKernelGGL(ffm_fused, dim3(BATCH / 4), dim3(256), 0, stream,
                           dense, sparse, w0, w, v4, out);
    }
}